// Round 3
// baseline (152.474 us; speedup 1.0000x reference)
//
#include <hip/hip_runtime.h>

typedef float f32x4 __attribute__((ext_vector_type(4)));
typedef float f32x16 __attribute__((ext_vector_type(16)));
typedef short s16x8 __attribute__((ext_vector_type(8)));
typedef unsigned int u32x2 __attribute__((ext_vector_type(2)));
typedef unsigned int u32x4 __attribute__((ext_vector_type(4)));

#define DEVFN static __device__ __forceinline__

constexpr int S_ = 2048;   // sequence (also group-position count)
constexpr int E_ = 512;    // embed
constexpr int D_ = 8;      // head dim
constexpr int P_ = 64;     // qkv proj dim
// 1/(sqrt(8)*ln2)  : exp((s)/sqrt(8)) == exp2(s * C2)
constexpr float C2 = 0.35355339059327373f * 1.4426950408889634f;

// Grouping (reshape trap): reference reshapes (B,S,64)->(64,2048,8) row-major:
// group g = b*8 + (s>>8), position p = (s&255)*8 + head, d = channel&7.

// workspace layout (bytes) -- small (~2.4 MB): flag + WT + WUT + ATT
constexpr size_t FLAG_OFF = 0;
constexpr size_t WT_OFF   = 256;                                 // Wt[192][512] bf16
constexpr size_t WUT_OFF  = WT_OFF  + (size_t)192 * 512 * 2;     // Wut[512][64] bf16
constexpr size_t ATT_OFF  = WUT_OFF + (size_t)512 * 64 * 2;      // attn [16384][64] bf16
// Q/K/V^T scratch lives in d_out (33.5MB); out_kernel later overwrites all of it.
constexpr size_t QG_O  = 0;                                      // Q [64g][2048][8] bf16
constexpr size_t KG_O  = (size_t)64 * 2048 * 8 * 2;              // K [64g][2048][8] bf16
constexpr size_t VTG_O = KG_O * 2;                               // V^T [64g][p8][d][8] bf16

DEVFN short f2bf(float f) {  // fp32 -> bf16 (RNE)
  unsigned u = __builtin_bit_cast(unsigned, f);
  return (short)((u + 0x7FFFu + ((u >> 16) & 1u)) >> 16);
}

DEVFN unsigned pkbf(float lo, float hi) {  // packed bf16 pair
  unsigned r;
  asm("v_cvt_pk_bf16_f32 %0, %1, %2" : "=v"(r) : "v"(lo), "v"(hi));
  return r;
}

DEVFN f32x16 mfma32(s16x8 a, s16x8 b, f32x16 c) {
  return __builtin_amdgcn_mfma_f32_32x32x16_bf16(a, b, c, 0, 0, 0);
}

DEVFN f32x16 zero16() {
  f32x16 z = {0,0,0,0,0,0,0,0,0,0,0,0,0,0,0,0};
  return z;
}

// ---------------- kernel 0: weight prep (bf16 transposed) + mask-zero flag --------
__global__ __launch_bounds__(256)
void prep_kernel(const float* __restrict__ Wq, const float* __restrict__ Wk,
                 const float* __restrict__ Wv, const float* __restrict__ Wu,
                 const float* __restrict__ maskm, short* __restrict__ WT,
                 short* __restrict__ WUT, int* __restrict__ flag)
{
  int bid = blockIdx.x, tid = threadIdx.x;
  if (bid < 48) {                       // Wt[n][k] = W[k][n], n<192 k<512
    int base = (bid * 256 + tid) * 8;
#pragma unroll
    for (int j = 0; j < 8; ++j) {
      int idx = base + j;
      int n = idx >> 9, k = idx & 511;
      const float* W = (n < 64) ? Wq : ((n < 128) ? Wk : Wv);
      WT[idx] = f2bf(W[k * 64 + (n & 63)]);
    }
  } else if (bid < 56) {                // Wut[n][k] = Wu[k][n], n<512 k<64
    int base = ((bid - 48) * 256 + tid) * 16;
#pragma unroll
    for (int j = 0; j < 16; ++j) {
      int idx = base + j;
      int n = idx >> 6, k = idx & 63;
      WUT[idx] = f2bf(Wu[k * 512 + n]);
    }
  } else {                              // mask all-zero check (256 blocks)
    const f32x4* m4 = (const f32x4*)maskm;
    int base = (bid - 56) * 4096;
    unsigned any = 0;
#pragma unroll
    for (int i = 0; i < 16; ++i) {
      f32x4 v = m4[base + i * 256 + tid];
      any |= __builtin_bit_cast(unsigned, v[0]) | __builtin_bit_cast(unsigned, v[1])
           | __builtin_bit_cast(unsigned, v[2]) | __builtin_bit_cast(unsigned, v[3]);
    }
    if (any != 0) atomicOr(flag, 1);    // -0.0 counted nonzero: safe (slow path only)
  }
}

// ---------------- kernel 1: QKV projection  x[16384,512] @ W -> bf16 group layouts
__global__ __launch_bounds__(384)
void proj_kernel(const float* __restrict__ x, const short* __restrict__ WT,
                 const float* __restrict__ bq, const float* __restrict__ bk,
                 const float* __restrict__ bv, short* __restrict__ QG,
                 short* __restrict__ KG, short* __restrict__ VTG)
{
  __shared__ short xl[32 * 520];        // x tile bf16, row stride 520 (bank pad)
  int tid = threadIdx.x;
  int mb = blockIdx.x * 32;
  for (int i = tid; i < 32 * 128; i += 384) {
    int row = i >> 7, c4 = i & 127;
    f32x4 v = *(const f32x4*)(x + (size_t)(mb + row) * E_ + c4 * 4);
    u32x2 w;
    w[0] = pkbf(v[0], v[1]);
    w[1] = pkbf(v[2], v[3]);
    *(u32x2*)(&xl[row * 520 + c4 * 4]) = w;
  }
  __syncthreads();
  int lane = tid & 63, wvi = tid >> 6;  // 6 waves, each an n-strip of 32
  int l31 = lane & 31, h = lane >> 5;
  int nstrip = wvi * 32;
  f32x16 acc = zero16();
#pragma unroll 4
  for (int kk = 0; kk < E_; kk += 16) { // C^T = Wt * x^T
    s16x8 af = *(const s16x8*)(WT + (size_t)(nstrip + l31) * E_ + kk + 8 * h);
    s16x8 bf = *(const s16x8*)(&xl[l31 * 520 + kk + 8 * h]);
    acc = mfma32(af, bf, acc);
  }
  int token = mb + l31;
  int bidx = token >> 11, s = token & 2047;
  int gg = bidx * 8 + (s >> 8);         // group = batch*8 + chunk
#pragma unroll
  for (int i = 0; i < 4; ++i) {
    int n0 = nstrip + 8 * i + 4 * h;    // 4 consecutive n per reg quad
    int proj = n0 >> 6;
    int wi = n0 & 63;
    int head = wi >> 3, db = wi & 7;    // db = 4h
    const float* bias = (proj == 0) ? bq : ((proj == 1) ? bk : bv);
    float f0 = acc[4*i+0] + bias[wi+0];
    float f1 = acc[4*i+1] + bias[wi+1];
    float f2 = acc[4*i+2] + bias[wi+2];
    float f3 = acc[4*i+3] + bias[wi+3];
    int p = ((s & 255) << 3) + head;    // group position = (s%256)*8 + head
    if (proj == 2) {                    // V^T: [g][p>>3][d][p&7] = [g][s&255][d][head]
      size_t vb = (size_t)gg * (S_ * D_) + (size_t)(s & 255) * 64 + head;
      VTG[vb + (db+0)*8] = f2bf(f0);
      VTG[vb + (db+1)*8] = f2bf(f1);
      VTG[vb + (db+2)*8] = f2bf(f2);
      VTG[vb + (db+3)*8] = f2bf(f3);
    } else {
      short* dst = (proj == 0) ? QG : KG;
      u32x2 o;
      o[0] = pkbf(f0, f1);
      o[1] = pkbf(f2, f3);
      *(u32x2*)(dst + ((size_t)gg * S_ + p) * D_ + db) = o;
    }
  }
}

// ---------------- kernel 2: fused attention (no-max softmax, direct denominator) --
__global__ __launch_bounds__(256)
void attn_kernel(const short* __restrict__ QG, const short* __restrict__ KG,
                 const short* __restrict__ VTG, const float* __restrict__ maskm,
                 const int* __restrict__ flag, short* __restrict__ ATT)
{
  __shared__ short K_lds[S_ * D_];      // [pos][8]       32KB
  __shared__ short V_lds[S_ * D_];      // [p8][d][8]     32KB
  __shared__ short P_lds[4][32][40];    // per-wave P^T round-trip, stride-40 pad
  int bid = blockIdx.x;
  int swz = (bid & 7) * 128 + (bid >> 3);   // XCD-chunked swizzle (1024 = 8*128)
  int g  = swz >> 4;
  int qb = (swz & 15) * 128;
  int tid = threadIdx.x;
  {
    const u32x4* ks = (const u32x4*)(KG  + (size_t)g * (S_ * D_));
    const u32x4* vs = (const u32x4*)(VTG + (size_t)g * (S_ * D_));
    u32x4* kd = (u32x4*)K_lds;
    u32x4* vd = (u32x4*)V_lds;
    for (int c = tid; c < (S_ * D_) / 8; c += 256) { kd[c] = ks[c]; vd[c] = vs[c]; }
  }
  __syncthreads();

  int lane = tid & 63, wvi = tid >> 6;  // 4 waves, each a 32-q strip
  int l31 = lane & 31, h = lane >> 5;
  int q = qb + wvi * 32 + l31;          // this lane's q position (accumulator column)
  bool hi = (h != 0);
  int d = l31;                          // V^T row supplied by this lane (A operand)
  s16x8 zero8 = {0,0,0,0,0,0,0,0};

  s16x8 qf = hi ? zero8
                : *(const s16x8*)(QG + ((size_t)g * S_ + q) * D_);
  f32x16 acc = zero16();
  float den = 0.0f;
  bool usemask = (*flag != 0);

  for (int kb = 0; kb < S_; kb += 32) {
    // S^T tile = K * Q^T  (rows=key-pos, cols=q-pos)
    s16x8 kf = hi ? zero8 : *(const s16x8*)(&K_lds[(kb + l31) * D_]);
    f32x16 st = mfma32(kf, qf, zero16());
    float p[16];
    if (!usemask) {
#pragma unroll
      for (int r = 0; r < 16; ++r) p[r] = exp2f(st[r] * C2);
    } else {
#pragma unroll
      for (int r = 0; r < 16; ++r) {
        int key = kb + (r & 3) + 8 * (r >> 2) + 4 * h;
        p[r] = exp2f((st[r] + maskm[(size_t)q * S_ + key]) * C2);
      }
    }
#pragma unroll
    for (int r = 0; r < 16; ++r) den += p[r];
    // P^T round-trip through wave-private LDS (transpose to B-fragment order).
    // p[4ri+j] is key kb+8ri+4h+j for column q=l31: write 4 shorts at [l31][8ri+4h].
#pragma unroll
    for (int ri = 0; ri < 4; ++ri) {
      u32x2 w;
      w[0] = pkbf(p[4*ri+0], p[4*ri+1]);
      w[1] = pkbf(p[4*ri+2], p[4*ri+3]);
      *(u32x2*)(&P_lds[wvi][l31][8*ri + 4*h]) = w;
    }
    // B-fragment: elem j = local key 8h+j (b1), 16+8h+j (b2), col=l31
    s16x8 b1 = *(const s16x8*)(&P_lds[wvi][l31][8*h]);
    s16x8 b2 = *(const s16x8*)(&P_lds[wvi][l31][16 + 8*h]);
    // V^T A-fragments: row d, keys kb+8h+j / kb+16+8h+j
    s16x8 va1 = zero8, va2 = zero8;
    if (d < 8) {
      va1 = *(const s16x8*)(&V_lds[((kb >> 3) + h) * 64 + d * 8]);
      va2 = *(const s16x8*)(&V_lds[((kb >> 3) + 2 + h) * 64 + d * 8]);
    }
    acc = mfma32(va1, b1, acc);
    acc = mfma32(va2, b2, acc);
  }
  den += __shfl_xor(den, 32, 64);       // partner half holds the other 16 keys/tile
  float inv = 1.0f / den;
  u32x2 o;
  o[0] = pkbf(acc[0] * inv, acc[1] * inv);
  o[1] = pkbf(acc[2] * inv, acc[3] * inv);
  // inverse reshape: token = (g>>3)*S + (g&7)*256 + (q>>3); channel = (q&7)*8 + d
  size_t token = (size_t)(g >> 3) * S_ + (g & 7) * 256 + (q >> 3);
  int cbase = (q & 7) * 8 + 4 * h;      // d rows: h=0 -> 0..3, h=1 -> 4..7
  *(u32x2*)(ATT + token * P_ + cbase) = o;
}

// ---------------- kernel 3: out = attn[16384,64] @ Wu[64,512] + bu ---------------
__global__ __launch_bounds__(256)
void out_kernel(const short* __restrict__ ATT, const short* __restrict__ WUT,
                const float* __restrict__ bu, float* __restrict__ out)
{
  int tid = threadIdx.x;
  int lane = tid & 63, wvi = tid >> 6;
  int l31 = lane & 31, h = lane >> 5;
  int mb = blockIdx.x * 32;
  int nb = wvi * 128;
  f32x16 acc[4];
#pragma unroll
  for (int nf = 0; nf < 4; ++nf) acc[nf] = zero16();
#pragma unroll
  for (int kk = 0; kk < 64; kk += 16) {
    s16x8 af = *(const s16x8*)(ATT + (size_t)(mb + l31) * P_ + kk + 8 * h);
#pragma unroll
    for (int nf = 0; nf < 4; ++nf) {
      s16x8 bf = *(const s16x8*)(WUT + (size_t)(nb + nf * 32 + l31) * P_ + kk + 8 * h);
      acc[nf] = mfma32(af, bf, acc[nf]);
    }
  }
#pragma unroll
  for (int nf = 0; nf < 4; ++nf) {
    int n = nb + nf * 32 + l31;
    float bias = bu[n];
#pragma unroll
    for (int r = 0; r < 16; ++r) {
      int m = (r & 3) + 8 * (r >> 2) + 4 * h;
      out[(size_t)(mb + m) * E_ + n] = acc[nf][r] + bias;
    }
  }
}

extern "C" void kernel_launch(void* const* d_in, const int* in_sizes, int n_in,
                              void* d_out, int out_size, void* d_ws, size_t ws_size,
                              hipStream_t stream) {
  const float* x     = (const float*)d_in[0];
  const float* maskm = (const float*)d_in[1];
  const float* Wq    = (const float*)d_in[2];
  const float* bq    = (const float*)d_in[3];
  const float* Wk    = (const float*)d_in[4];
  const float* bk    = (const float*)d_in[5];
  const float* Wv    = (const float*)d_in[6];
  const float* bv    = (const float*)d_in[7];
  const float* Wu    = (const float*)d_in[8];
  const float* bu    = (const float*)d_in[9];
  float* out = (float*)d_out;
  char* ws = (char*)d_ws;
  char* ob = (char*)d_out;
  int*   flag = (int*)(ws + FLAG_OFF);
  short* WT   = (short*)(ws + WT_OFF);
  short* WUT  = (short*)(ws + WUT_OFF);
  short* ATT  = (short*)(ws + ATT_OFF);
  short* QG   = (short*)(ob + QG_O);    // d_out used as scratch; out_kernel
  short* KG   = (short*)(ob + KG_O);    // rewrites every byte of d_out last.
  short* VTG  = (short*)(ob + VTG_O);

  hipMemsetAsync(flag, 0, 16, stream);
  prep_kernel<<<312, 256, 0, stream>>>(Wq, Wk, Wv, Wu, maskm, WT, WUT, flag);
  proj_kernel<<<512, 384, 0, stream>>>(x, WT, bq, bk, bv, QG, KG, VTG);
  attn_kernel<<<1024, 256, 0, stream>>>(QG, KG, VTG, maskm, flag, ATT);
  out_kernel<<<512, 256, 0, stream>>>(ATT, WUT, bu, out);
}

// Round 5
// 119.749 us; speedup vs baseline: 1.2733x; 1.2733x over previous
//
#include <hip/hip_runtime.h>

typedef float f32x4 __attribute__((ext_vector_type(4)));
typedef float f32x16 __attribute__((ext_vector_type(16)));
typedef short s16x8 __attribute__((ext_vector_type(8)));
typedef unsigned int u32x2 __attribute__((ext_vector_type(2)));
typedef unsigned int u32x4 __attribute__((ext_vector_type(4)));

#define DEVFN static __device__ __forceinline__

constexpr int S_ = 2048;   // sequence (also group-position count)
constexpr int E_ = 512;    // embed
constexpr int D_ = 8;      // head dim
constexpr int P_ = 64;     // qkv proj dim
// 1/(sqrt(8)*ln2)  : exp(s/sqrt(8)) == exp2(s * C2)
constexpr float C2 = 0.35355339059327373f * 1.4426950408889634f;

// Grouping (reshape trap): reference reshapes (B,S,64)->(64,2048,8) row-major:
// group g = b*8 + (s>>8), position p = (s&255)*8 + head, d = channel&7.

// workspace layout (bytes) -- keep small (~2.4 MB proven safe in round 3)
constexpr size_t FLAG_OFF = 0;
constexpr size_t WT_OFF   = 256;                                 // Wt[192][512] bf16
constexpr size_t WUT_OFF  = WT_OFF  + (size_t)192 * 512 * 2;     // Wut[512][64] bf16
constexpr size_t ATT_OFF  = WUT_OFF + (size_t)512 * 64 * 2;      // attn [16384][64] bf16
// Q/K/V^T scratch lives in d_out (33.5MB); out_kernel later overwrites all of it.
constexpr size_t QG_O  = 0;                                      // Q [64g][2048][8] bf16
constexpr size_t KG_O  = (size_t)64 * 2048 * 8 * 2;              // K [64g][2048][8] bf16
constexpr size_t VTG_O = KG_O * 2;                               // V^T [64g][p8][d][8] bf16

DEVFN short f2bf(float f) {  // fp32 -> bf16 (RNE)
  unsigned u = __builtin_bit_cast(unsigned, f);
  return (short)((u + 0x7FFFu + ((u >> 16) & 1u)) >> 16);
}

DEVFN unsigned pkbf(float lo, float hi) {  // packed bf16 pair
  unsigned r;
  asm("v_cvt_pk_bf16_f32 %0, %1, %2" : "=v"(r) : "v"(lo), "v"(hi));
  return r;
}

DEVFN float fexp2(float x) {  // raw v_exp_f32 (args bounded; no OCML fixups)
#if __has_builtin(__builtin_amdgcn_exp2f)
  return __builtin_amdgcn_exp2f(x);
#else
  return exp2f(x);
#endif
}

DEVFN f32x16 mfma32(s16x8 a, s16x8 b, f32x16 c) {
  return __builtin_amdgcn_mfma_f32_32x32x16_bf16(a, b, c, 0, 0, 0);
}

DEVFN f32x16 zero16() {
  f32x16 z = {0,0,0,0,0,0,0,0,0,0,0,0,0,0,0,0};
  return z;
}

// ---------------- kernel 0: weight prep (bf16 transposed) + mask-zero flag --------
__global__ __launch_bounds__(256)
void prep_kernel(const float* __restrict__ Wq, const float* __restrict__ Wk,
                 const float* __restrict__ Wv, const float* __restrict__ Wu,
                 const float* __restrict__ maskm, short* __restrict__ WT,
                 short* __restrict__ WUT, int* __restrict__ flag)
{
  int bid = blockIdx.x, tid = threadIdx.x;
  if (bid < 48) {                       // Wt[n][k] = W[k][n], n<192 k<512
    int base = (bid * 256 + tid) * 8;
#pragma unroll
    for (int j = 0; j < 8; ++j) {
      int idx = base + j;
      int n = idx >> 9, k = idx & 511;
      const float* W = (n < 64) ? Wq : ((n < 128) ? Wk : Wv);
      WT[idx] = f2bf(W[k * 64 + (n & 63)]);
    }
  } else if (bid < 56) {                // Wut[n][k] = Wu[k][n], n<512 k<64
    int base = ((bid - 48) * 256 + tid) * 16;
#pragma unroll
    for (int j = 0; j < 16; ++j) {
      int idx = base + j;
      int n = idx >> 6, k = idx & 63;
      WUT[idx] = f2bf(Wu[k * 512 + n]);
    }
  } else {                              // mask all-zero check (256 blocks)
    const f32x4* m4 = (const f32x4*)maskm;
    int base = (bid - 56) * 4096;
    unsigned any = 0;
#pragma unroll
    for (int i = 0; i < 16; ++i) {
      f32x4 v = m4[base + i * 256 + tid];
      any |= __builtin_bit_cast(unsigned, v[0]) | __builtin_bit_cast(unsigned, v[1])
           | __builtin_bit_cast(unsigned, v[2]) | __builtin_bit_cast(unsigned, v[3]);
    }
    if (any != 0) atomicOr(flag, 1);    // -0.0 counted nonzero: safe (slow path only)
  }
}

// ---------------- kernel 1: QKV projection  x[16384,512] @ W -> bf16 group layouts
// Q is pre-scaled by C2 so attn logits come out of the MFMA ready for exp2.
__global__ __launch_bounds__(384)
void proj_kernel(const float* __restrict__ x, const short* __restrict__ WT,
                 const float* __restrict__ bq, const float* __restrict__ bk,
                 const float* __restrict__ bv, short* __restrict__ QG,
                 short* __restrict__ KG, short* __restrict__ VTG)
{
  __shared__ short xl[32 * 520];        // x tile bf16, row stride 520 (bank pad)
  int tid = threadIdx.x;
  int mb = blockIdx.x * 32;
  for (int i = tid; i < 32 * 128; i += 384) {
    int row = i >> 7, c4 = i & 127;
    f32x4 v = *(const f32x4*)(x + (size_t)(mb + row) * E_ + c4 * 4);
    u32x2 w;
    w[0] = pkbf(v[0], v[1]);
    w[1] = pkbf(v[2], v[3]);
    *(u32x2*)(&xl[row * 520 + c4 * 4]) = w;
  }
  __syncthreads();
  int lane = tid & 63, wvi = tid >> 6;  // 6 waves, each an n-strip of 32
  int l31 = lane & 31, h = lane >> 5;
  int nstrip = wvi * 32;
  f32x16 acc = zero16();
#pragma unroll 4
  for (int kk = 0; kk < E_; kk += 16) { // C^T = Wt * x^T
    s16x8 af = *(const s16x8*)(WT + (size_t)(nstrip + l31) * E_ + kk + 8 * h);
    s16x8 bf = *(const s16x8*)(&xl[l31 * 520 + kk + 8 * h]);
    acc = mfma32(af, bf, acc);
  }
  int token = mb + l31;
  int bidx = token >> 11, s = token & 2047;
  int gg = bidx * 8 + (s >> 8);         // group = batch*8 + chunk
#pragma unroll
  for (int i = 0; i < 4; ++i) {
    int n0 = nstrip + 8 * i + 4 * h;    // 4 consecutive n per reg quad
    int proj = n0 >> 6;
    int wi = n0 & 63;
    int head = wi >> 3, db = wi & 7;    // db = 4h
    const float* bias = (proj == 0) ? bq : ((proj == 1) ? bk : bv);
    float sc = (proj == 0) ? C2 : 1.0f; // fold softmax scale into Q
    float f0 = (acc[4*i+0] + bias[wi+0]) * sc;
    float f1 = (acc[4*i+1] + bias[wi+1]) * sc;
    float f2 = (acc[4*i+2] + bias[wi+2]) * sc;
    float f3 = (acc[4*i+3] + bias[wi+3]) * sc;
    int p = ((s & 255) << 3) + head;    // group position = (s%256)*8 + head
    if (proj == 2) {                    // V^T: [g][p>>3][d][p&7] = [g][s&255][d][head]
      size_t vb = (size_t)gg * (S_ * D_) + (size_t)(s & 255) * 64 + head;
      VTG[vb + (db+0)*8] = f2bf(f0);
      VTG[vb + (db+1)*8] = f2bf(f1);
      VTG[vb + (db+2)*8] = f2bf(f2);
      VTG[vb + (db+3)*8] = f2bf(f3);
    } else {
      short* dst = (proj == 0) ? QG : KG;
      u32x2 o;
      o[0] = pkbf(f0, f1);
      o[1] = pkbf(f2, f3);
      *(u32x2*)(dst + ((size_t)gg * S_ + p) * D_ + db) = o;
    }
  }
}

// ---------------- kernel 2: fused attention (no-max softmax, ones-row denom,
//                            LDS round-trip P^T -- no permlane anywhere) ----------
__global__ __launch_bounds__(256)
void attn_kernel(const short* __restrict__ QG, const short* __restrict__ KG,
                 const short* __restrict__ VTG, const float* __restrict__ maskm,
                 const int* __restrict__ flag, short* __restrict__ ATT)
{
  __shared__ short K_lds[S_ * D_];      // [pos][8]       32KB
  __shared__ short V_lds[S_ * D_];      // [p8][d][8]     32KB
  __shared__ short P_lds[4][32][36];    // per-wave P^T round-trip, stride-36 pad
  int bid = blockIdx.x;
  int swz = (bid & 7) * 128 + (bid >> 3);   // XCD-chunked swizzle (1024 = 8*128)
  int g  = swz >> 4;
  int qb = (swz & 15) * 128;
  int tid = threadIdx.x;
  {
    const u32x4* ks = (const u32x4*)(KG  + (size_t)g * (S_ * D_));
    const u32x4* vs = (const u32x4*)(VTG + (size_t)g * (S_ * D_));
    u32x4* kd = (u32x4*)K_lds;
    u32x4* vd = (u32x4*)V_lds;
    for (int c = tid; c < (S_ * D_) / 8; c += 256) { kd[c] = ks[c]; vd[c] = vs[c]; }
  }
  __syncthreads();

  int lane = tid & 63, wvi = tid >> 6;  // 4 waves, each a 32-q strip
  int l31 = lane & 31, h = lane >> 5;
  int q = qb + wvi * 32 + l31;          // this lane's q position (accumulator column)
  bool hi = (h != 0);
  int d = l31;                          // V^T row supplied by this lane (A operand)
  s16x8 zero8 = {0,0,0,0,0,0,0,0};
  short onebf = (short)0x3F80;
  s16x8 ones8 = {onebf,onebf,onebf,onebf,onebf,onebf,onebf,onebf};

  s16x8 qf = hi ? zero8
                : *(const s16x8*)(QG + ((size_t)g * S_ + q) * D_);
  f32x16 acc = zero16();
  bool usemask = (*flag != 0);

  for (int kb = 0; kb < S_; kb += 32) {
    // S^T tile = K * Q^T  (rows=key-pos, cols=q-pos); Q pre-scaled by C2
    s16x8 kf = hi ? zero8 : *(const s16x8*)(&K_lds[(kb + l31) * D_]);
    f32x16 st = mfma32(kf, qf, zero16());
    float p[16];
    if (!usemask) {
#pragma unroll
      for (int r = 0; r < 16; ++r) p[r] = fexp2(st[r]);
    } else {
#pragma unroll
      for (int r = 0; r < 16; ++r) {
        int key = kb + (r & 3) + 8 * (r >> 2) + 4 * h;
        p[r] = fexp2(st[r] + maskm[(size_t)q * S_ + key] * C2);
      }
    }
    // P^T round-trip through wave-private LDS (transpose to B-fragment order).
    // p[4ri+j] is key kb+8ri+4h+j for column q=l31: write 4 shorts at [l31][8ri+4h].
#pragma unroll
    for (int ri = 0; ri < 4; ++ri) {
      u32x2 w;
      w[0] = pkbf(p[4*ri+0], p[4*ri+1]);
      w[1] = pkbf(p[4*ri+2], p[4*ri+3]);
      *(u32x2*)(&P_lds[wvi][l31][8*ri + 4*h]) = w;
    }
    // B-fragment: elem j = local key 8h+j (b1), 16+8h+j (b2), col=l31
    s16x8 b1 = *(const s16x8*)(&P_lds[wvi][l31][8*h]);
    s16x8 b2 = *(const s16x8*)(&P_lds[wvi][l31][16 + 8*h]);
    // V_aug^T A-fragments: rows d (0..7 = V, 8 = ones -> denominator in C row 8)
    s16x8 va1 = zero8, va2 = zero8;
    if (d < 8) {
      va1 = *(const s16x8*)(&V_lds[((kb >> 3) + h) * 64 + d * 8]);
      va2 = *(const s16x8*)(&V_lds[((kb >> 3) + 2 + h) * 64 + d * 8]);
    } else if (d == 8) { va1 = ones8; va2 = ones8; }
    acc = mfma32(va1, b1, acc);
    acc = mfma32(va2, b2, acc);
  }
  // denominator: C row 8 = acc[4] of h=0 lanes; broadcast to h=1 half via shfl
  float d0 = acc[4];
  float dp = __shfl_xor(d0, 32, 64);
  float den = hi ? dp : d0;
  float inv = __builtin_amdgcn_rcpf(den);
  u32x2 o;
  o[0] = pkbf(acc[0] * inv, acc[1] * inv);
  o[1] = pkbf(acc[2] * inv, acc[3] * inv);
  // inverse reshape: token = (g>>3)*S + (g&7)*256 + (q>>3); channel = (q&7)*8 + d
  size_t token = (size_t)(g >> 3) * S_ + (g & 7) * 256 + (q >> 3);
  int cbase = (q & 7) * 8 + 4 * h;      // d rows: h=0 -> 0..3, h=1 -> 4..7
  *(u32x2*)(ATT + token * P_ + cbase) = o;
}

// ---------------- kernel 3: out = attn[16384,64] @ Wu[64,512] + bu ---------------
__global__ __launch_bounds__(256)
void out_kernel(const short* __restrict__ ATT, const short* __restrict__ WUT,
                const float* __restrict__ bu, float* __restrict__ out)
{
  int tid = threadIdx.x;
  int lane = tid & 63, wvi = tid >> 6;
  int l31 = lane & 31, h = lane >> 5;
  int mb = blockIdx.x * 32;
  int nb = wvi * 128;
  f32x16 acc[4];
#pragma unroll
  for (int nf = 0; nf < 4; ++nf) acc[nf] = zero16();
#pragma unroll
  for (int kk = 0; kk < 64; kk += 16) {
    s16x8 af = *(const s16x8*)(ATT + (size_t)(mb + l31) * P_ + kk + 8 * h);
#pragma unroll
    for (int nf = 0; nf < 4; ++nf) {
      s16x8 bf = *(const s16x8*)(WUT + (size_t)(nb + nf * 32 + l31) * P_ + kk + 8 * h);
      acc[nf] = mfma32(af, bf, acc[nf]);
    }
  }
#pragma unroll
  for (int nf = 0; nf < 4; ++nf) {
    int n = nb + nf * 32 + l31;
    float bias = bu[n];
#pragma unroll
    for (int r = 0; r < 16; ++r) {
      int m = (r & 3) + 8 * (r >> 2) + 4 * h;
      out[(size_t)(mb + m) * E_ + n] = acc[nf][r] + bias;
    }
  }
}

extern "C" void kernel_launch(void* const* d_in, const int* in_sizes, int n_in,
                              void* d_out, int out_size, void* d_ws, size_t ws_size,
                              hipStream_t stream) {
  const float* x     = (const float*)d_in[0];
  const float* maskm = (const float*)d_in[1];
  const float* Wq    = (const float*)d_in[2];
  const float* bq    = (const float*)d_in[3];
  const float* Wk    = (const float*)d_in[4];
  const float* bk    = (const float*)d_in[5];
  const float* Wv    = (const float*)d_in[6];
  const float* bv    = (const float*)d_in[7];
  const float* Wu    = (const float*)d_in[8];
  const float* bu    = (const float*)d_in[9];
  float* out = (float*)d_out;
  char* ws = (char*)d_ws;
  char* ob = (char*)d_out;
  int*   flag = (int*)(ws + FLAG_OFF);
  short* WT   = (short*)(ws + WT_OFF);
  short* WUT  = (short*)(ws + WUT_OFF);
  short* ATT  = (short*)(ws + ATT_OFF);
  short* QG   = (short*)(ob + QG_O);    // d_out used as scratch; out_kernel
  short* KG   = (short*)(ob + KG_O);    // rewrites every byte of d_out last.
  short* VTG  = (short*)(ob + VTG_O);

  hipMemsetAsync(flag, 0, 16, stream);
  prep_kernel<<<312, 256, 0, stream>>>(Wq, Wk, Wv, Wu, maskm, WT, WUT, flag);
  proj_kernel<<<512, 384, 0, stream>>>(x, WT, bq, bk, bv, QG, KG, VTG);
  attn_kernel<<<1024, 256, 0, stream>>>(QG, KG, VTG, maskm, flag, ATT);
  out_kernel<<<512, 256, 0, stream>>>(ATT, WUT, bu, out);
}

// Round 6
// 76.506 us; speedup vs baseline: 1.9930x; 1.5652x over previous
//
#include <hip/hip_runtime.h>

typedef float f32x4 __attribute__((ext_vector_type(4)));
typedef float f32x16 __attribute__((ext_vector_type(16)));
typedef short s16x8 __attribute__((ext_vector_type(8)));
typedef unsigned int u32x2 __attribute__((ext_vector_type(2)));
typedef unsigned int u32x4 __attribute__((ext_vector_type(4)));

#define DEVFN static __device__ __forceinline__

constexpr int S_ = 2048;   // sequence (also group-position count)
constexpr int E_ = 512;    // embed
constexpr int D_ = 8;      // head dim
constexpr int P_ = 64;     // qkv proj dim
// 1/(sqrt(8)*ln2)  : exp(s/sqrt(8)) == exp2(s * C2)
constexpr float C2 = 0.35355339059327373f * 1.4426950408889634f;

// Grouping (reshape trap): reference reshapes (B,S,64)->(64,2048,8) row-major:
// group g = b*8 + (s>>8), position p = (s&255)*8 + head, d = channel&7.

// workspace layout (bytes) -- keep small (~2.4 MB proven safe in round 3)
constexpr size_t FLAG_OFF = 0;
constexpr size_t WT_OFF   = 256;                                 // Wt[192][512] bf16
constexpr size_t WUT_OFF  = WT_OFF  + (size_t)192 * 512 * 2;     // Wut[512][64] bf16
constexpr size_t ATT_OFF  = WUT_OFF + (size_t)512 * 64 * 2;      // attn [16384][64] bf16
// Q/K/V^T scratch lives in d_out (33.5MB); out_kernel later overwrites all of it.
constexpr size_t QG_O  = 0;                                      // Q [64g][2048][8] bf16
constexpr size_t KG_O  = (size_t)64 * 2048 * 8 * 2;              // K [64g][2048][8] bf16
constexpr size_t VTG_O = KG_O * 2;  // V^T [64g][t128][d8][16 pi-slots] bf16

DEVFN short f2bf(float f) {  // fp32 -> bf16 (RNE)
  unsigned u = __builtin_bit_cast(unsigned, f);
  return (short)((u + 0x7FFFu + ((u >> 16) & 1u)) >> 16);
}

DEVFN unsigned pkbf(float lo, float hi) {  // packed bf16 pair
  unsigned r;
  asm("v_cvt_pk_bf16_f32 %0, %1, %2" : "=v"(r) : "v"(lo), "v"(hi));
  return r;
}

DEVFN float fexp2(float x) {  // raw v_exp_f32 (args bounded; no OCML fixups)
#if __has_builtin(__builtin_amdgcn_exp2f)
  return __builtin_amdgcn_exp2f(x);
#else
  return exp2f(x);
#endif
}

DEVFN f32x16 mfma32(s16x8 a, s16x8 b, f32x16 c) {
  return __builtin_amdgcn_mfma_f32_32x32x16_bf16(a, b, c, 0, 0, 0);
}

DEVFN f32x16 zero16() {
  f32x16 z = {0,0,0,0,0,0,0,0,0,0,0,0,0,0,0,0};
  return z;
}

// ---------------- kernel 0: weight prep (bf16 transposed) + mask-zero flag --------
__global__ __launch_bounds__(256)
void prep_kernel(const float* __restrict__ Wq, const float* __restrict__ Wk,
                 const float* __restrict__ Wv, const float* __restrict__ Wu,
                 const float* __restrict__ maskm, short* __restrict__ WT,
                 short* __restrict__ WUT, int* __restrict__ flag)
{
  int bid = blockIdx.x, tid = threadIdx.x;
  if (bid < 48) {                       // Wt[n][k] = W[k][n], n<192 k<512
    int base = (bid * 256 + tid) * 8;
#pragma unroll
    for (int j = 0; j < 8; ++j) {
      int idx = base + j;
      int n = idx >> 9, k = idx & 511;
      const float* W = (n < 64) ? Wq : ((n < 128) ? Wk : Wv);
      WT[idx] = f2bf(W[k * 64 + (n & 63)]);
    }
  } else if (bid < 56) {                // Wut[n][k] = Wu[k][n], n<512 k<64
    int base = ((bid - 48) * 256 + tid) * 16;
#pragma unroll
    for (int j = 0; j < 16; ++j) {
      int idx = base + j;
      int n = idx >> 6, k = idx & 63;
      WUT[idx] = f2bf(Wu[k * 512 + n]);
    }
  } else {                              // mask all-zero check (256 blocks)
    const f32x4* m4 = (const f32x4*)maskm;
    int base = (bid - 56) * 4096;
    unsigned any = 0;
#pragma unroll
    for (int i = 0; i < 16; ++i) {
      f32x4 v = m4[base + i * 256 + tid];
      any |= __builtin_bit_cast(unsigned, v[0]) | __builtin_bit_cast(unsigned, v[1])
           | __builtin_bit_cast(unsigned, v[2]) | __builtin_bit_cast(unsigned, v[3]);
    }
    if (any != 0) atomicOr(flag, 1);    // -0.0 counted nonzero: safe (slow path only)
  }
}

// ---------------- kernel 1: QKV projection  x[16384,512] @ W -> bf16 group layouts
// Q is pre-scaled by C2 so attn logits come out of the MFMA ready for exp2.
// V^T written in pi-permuted 16-key-block layout [g][t][d][slot] so attn's PV
// A-operand key order matches the QK C-layout key order (no P transpose needed).
__global__ __launch_bounds__(384)
void proj_kernel(const float* __restrict__ x, const short* __restrict__ WT,
                 const float* __restrict__ bq, const float* __restrict__ bk,
                 const float* __restrict__ bv, short* __restrict__ QG,
                 short* __restrict__ KG, short* __restrict__ VTG)
{
  __shared__ short xl[32 * 520];        // x tile bf16, row stride 520 (bank pad)
  int tid = threadIdx.x;
  int mb = blockIdx.x * 32;
  for (int i = tid; i < 32 * 128; i += 384) {
    int row = i >> 7, c4 = i & 127;
    f32x4 v = *(const f32x4*)(x + (size_t)(mb + row) * E_ + c4 * 4);
    u32x2 w;
    w[0] = pkbf(v[0], v[1]);
    w[1] = pkbf(v[2], v[3]);
    *(u32x2*)(&xl[row * 520 + c4 * 4]) = w;
  }
  __syncthreads();
  int lane = tid & 63, wvi = tid >> 6;  // 6 waves, each an n-strip of 32
  int l31 = lane & 31, h = lane >> 5;
  int nstrip = wvi * 32;
  f32x16 acc = zero16();
#pragma unroll 4
  for (int kk = 0; kk < E_; kk += 16) { // C^T = Wt * x^T
    s16x8 af = *(const s16x8*)(WT + (size_t)(nstrip + l31) * E_ + kk + 8 * h);
    s16x8 bf = *(const s16x8*)(&xl[l31 * 520 + kk + 8 * h]);
    acc = mfma32(af, bf, acc);
  }
  int token = mb + l31;
  int bidx = token >> 11, s = token & 2047;
  int gg = bidx * 8 + (s >> 8);         // group = batch*8 + chunk
#pragma unroll
  for (int i = 0; i < 4; ++i) {
    int n0 = nstrip + 8 * i + 4 * h;    // 4 consecutive n per reg quad
    int proj = n0 >> 6;
    int wi = n0 & 63;
    int head = wi >> 3, db = wi & 7;    // db = 4h
    const float* bias = (proj == 0) ? bq : ((proj == 1) ? bk : bv);
    float sc = (proj == 0) ? C2 : 1.0f; // fold softmax scale into Q
    float f0 = (acc[4*i+0] + bias[wi+0]) * sc;
    float f1 = (acc[4*i+1] + bias[wi+1]) * sc;
    float f2 = (acc[4*i+2] + bias[wi+2]) * sc;
    float f3 = (acc[4*i+3] + bias[wi+3]) * sc;
    int p = ((s & 255) << 3) + head;    // group position = (s%256)*8 + head
    if (proj == 2) {                    // V^T: [g][t=p>>4][d][sigma(p&15)]
      int k16 = p & 15;
      int slot = (k16 & 3) + ((k16 >> 2) & 1) * 8 + (k16 >> 3) * 4;
      size_t vb = (size_t)gg * (S_ * D_) + (size_t)(p >> 4) * 128 + slot;
      VTG[vb + (db+0)*16] = f2bf(f0);
      VTG[vb + (db+1)*16] = f2bf(f1);
      VTG[vb + (db+2)*16] = f2bf(f2);
      VTG[vb + (db+3)*16] = f2bf(f3);
    } else {
      short* dst = (proj == 0) ? QG : KG;
      u32x2 o;
      o[0] = pkbf(f0, f1);
      o[1] = pkbf(f2, f3);
      *(u32x2*)(dst + ((size_t)gg * S_ + p) * D_ + db) = o;
    }
  }
}

// ---------------- kernel 2: fused attention (no-max softmax, ones-row denom,
//      layout-matched PV: no P transpose, no shuffles, no per-tile selects) -------
__global__ __launch_bounds__(512, 4)
void attn_kernel(const short* __restrict__ QG, const short* __restrict__ KG,
                 const short* __restrict__ VTG, const float* __restrict__ maskm,
                 const int* __restrict__ flag, short* __restrict__ ATT)
{
  __shared__ short K_lds[S_ * D_];          // [key][8]            32KB
  __shared__ short V_lds[128 * 9 * 16];     // [t][d(8)+ones][16]  36KB
  __shared__ short Z_lds[8];                // zero block (h=1 K reads)
  int bid = blockIdx.x;
  int swz = (bid & 7) * 64 + (bid >> 3);    // XCD-chunked swizzle (512 = 8*64)
  int g  = swz >> 3;
  int qb = (swz & 7) * 256;
  int tid = threadIdx.x;
  {
    const u32x4* ks = (const u32x4*)(KG  + (size_t)g * (S_ * D_));
    const u32x4* vs = (const u32x4*)(VTG + (size_t)g * (S_ * D_));
    u32x4* kd = (u32x4*)K_lds;
#pragma unroll
    for (int it = 0; it < 4; ++it) {
      int i = tid + it * 512;
      kd[i] = ks[i];
      u32x4 v = vs[i];
      int t = i >> 4, rem = i & 15;         // rem = d*2 + half
      *(u32x4*)(&V_lds[t * 144 + rem * 8]) = v;
    }
    if (tid < 8) Z_lds[tid] = 0;
    unsigned one2 = 0x3F803F80u;            // ones row d=8 (denominator)
    u32x2 o2; o2[0] = one2; o2[1] = one2;
    int t = tid >> 2, qr = tid & 3;
    *(u32x2*)(&V_lds[t * 144 + 128 + qr * 4]) = o2;
  }
  __syncthreads();

  int lane = tid & 63, wvi = tid >> 6;      // 8 waves, each a 32-q strip
  int l31 = lane & 31, h = lane >> 5;
  int q = qb + wvi * 32 + l31;              // this lane's q position (C column)
  bool hi = (h != 0);
  int dcl = (l31 < 8) ? l31 : 8;            // V row (clamped to ones row)
  s16x8 zero8 = {0,0,0,0,0,0,0,0};

  s16x8 qf = hi ? zero8
                : *(const s16x8*)(QG + ((size_t)g * S_ + q) * D_);
  const short* kptr = hi ? Z_lds : &K_lds[l31 * 8];
  int kstride = hi ? 0 : 32 * 8;            // shorts per 32-key tile
  const short* vptr = &V_lds[dcl * 16 + 8 * h];
  f32x16 acc = zero16();
  bool usemask = (*flag != 0);

  for (int kb = 0; kb < S_; kb += 32) {
    // S^T tile = K * Q^T (rows=key, cols=q); Q pre-scaled by C2
    s16x8 kf = *(const s16x8*)kptr;
    kptr += kstride;
    f32x16 st = mfma32(kf, qf, zero16());
    s16x8 va1 = *(const s16x8*)vptr;         // keys pi-ordered {kb+0..3,8..11 | 4..7,12..15}
    s16x8 va2 = *(const s16x8*)(vptr + 144); // keys kb+16..31 same order
    vptr += 288;
    float p[16];                             // p[r] = key kb + (r&3)+8*(r>>2)+4h
    if (!usemask) {
#pragma unroll
      for (int r = 0; r < 16; ++r) p[r] = fexp2(st[r]);
    } else {
#pragma unroll
      for (int r = 0; r < 16; ++r) {
        int key = kb + (r & 3) + 8 * (r >> 2) + 4 * h;
        p[r] = fexp2(st[r] + maskm[(size_t)q * S_ + key] * C2);
      }
    }
    // B-fragments in native C-layout key order == V_lds pi order (no transpose!)
    u32x4 b1, b2;
    b1[0] = pkbf(p[0],  p[1]);
    b1[1] = pkbf(p[2],  p[3]);
    b1[2] = pkbf(p[4],  p[5]);
    b1[3] = pkbf(p[6],  p[7]);
    b2[0] = pkbf(p[8],  p[9]);
    b2[1] = pkbf(p[10], p[11]);
    b2[2] = pkbf(p[12], p[13]);
    b2[3] = pkbf(p[14], p[15]);
    acc = mfma32(va1, __builtin_bit_cast(s16x8, b1), acc);
    acc = mfma32(va2, __builtin_bit_cast(s16x8, b2), acc);
  }
  // denominator: C row 8 (ones row) = acc[4] of h=0 lanes; share via shfl
  float d0 = acc[4];
  float dp = __shfl_xor(d0, 32, 64);
  float den = hi ? dp : d0;
  float inv = __builtin_amdgcn_rcpf(den);
  u32x2 o;
  o[0] = pkbf(acc[0] * inv, acc[1] * inv);
  o[1] = pkbf(acc[2] * inv, acc[3] * inv);
  // inverse reshape: token = (g>>3)*S + (g&7)*256 + (q>>3); channel = (q&7)*8 + d
  size_t token = (size_t)(g >> 3) * S_ + (g & 7) * 256 + (q >> 3);
  int cbase = (q & 7) * 8 + 4 * h;          // d rows: h=0 -> 0..3, h=1 -> 4..7
  *(u32x2*)(ATT + token * P_ + cbase) = o;
}

// ---------------- kernel 3: out = attn[16384,64] @ Wu[64,512] + bu ---------------
__global__ __launch_bounds__(256)
void out_kernel(const short* __restrict__ ATT, const short* __restrict__ WUT,
                const float* __restrict__ bu, float* __restrict__ out)
{
  int tid = threadIdx.x;
  int lane = tid & 63, wvi = tid >> 6;
  int l31 = lane & 31, h = lane >> 5;
  int mb = blockIdx.x * 32;
  int nb = wvi * 128;
  f32x16 acc[4];
#pragma unroll
  for (int nf = 0; nf < 4; ++nf) acc[nf] = zero16();
#pragma unroll
  for (int kk = 0; kk < 64; kk += 16) {
    s16x8 af = *(const s16x8*)(ATT + (size_t)(mb + l31) * P_ + kk + 8 * h);
#pragma unroll
    for (int nf = 0; nf < 4; ++nf) {
      s16x8 bf = *(const s16x8*)(WUT + (size_t)(nb + nf * 32 + l31) * P_ + kk + 8 * h);
      acc[nf] = mfma32(af, bf, acc[nf]);
    }
  }
#pragma unroll
  for (int nf = 0; nf < 4; ++nf) {
    int n = nb + nf * 32 + l31;
    float bias = bu[n];
#pragma unroll
    for (int r = 0; r < 16; ++r) {
      int m = (r & 3) + 8 * (r >> 2) + 4 * h;
      out[(size_t)(mb + m) * E_ + n] = acc[nf][r] + bias;
    }
  }
}

extern "C" void kernel_launch(void* const* d_in, const int* in_sizes, int n_in,
                              void* d_out, int out_size, void* d_ws, size_t ws_size,
                              hipStream_t stream) {
  const float* x     = (const float*)d_in[0];
  const float* maskm = (const float*)d_in[1];
  const float* Wq    = (const float*)d_in[2];
  const float* bq    = (const float*)d_in[3];
  const float* Wk    = (const float*)d_in[4];
  const float* bk    = (const float*)d_in[5];
  const float* Wv    = (const float*)d_in[6];
  const float* bv    = (const float*)d_in[7];
  const float* Wu    = (const float*)d_in[8];
  const float* bu    = (const float*)d_in[9];
  float* out = (float*)d_out;
  char* ws = (char*)d_ws;
  char* ob = (char*)d_out;
  int*   flag = (int*)(ws + FLAG_OFF);
  short* WT   = (short*)(ws + WT_OFF);
  short* WUT  = (short*)(ws + WUT_OFF);
  short* ATT  = (short*)(ws + ATT_OFF);
  short* QG   = (short*)(ob + QG_O);    // d_out used as scratch; out_kernel
  short* KG   = (short*)(ob + KG_O);    // rewrites every byte of d_out last.
  short* VTG  = (short*)(ob + VTG_O);

  hipMemsetAsync(flag, 0, 16, stream);
  prep_kernel<<<312, 256, 0, stream>>>(Wq, Wk, Wv, Wu, maskm, WT, WUT, flag);
  proj_kernel<<<512, 384, 0, stream>>>(x, WT, bq, bk, bv, QG, KG, VTG);
  attn_kernel<<<512, 512, 0, stream>>>(QG, KG, VTG, maskm, flag, ATT);
  out_kernel<<<512, 256, 0, stream>>>(ATT, WUT, bu, out);
}

// Round 7
// 65.223 us; speedup vs baseline: 2.3377x; 1.1730x over previous
//
#include <hip/hip_runtime.h>

typedef float f32x4 __attribute__((ext_vector_type(4)));
typedef float f32x16 __attribute__((ext_vector_type(16)));
typedef short s16x8 __attribute__((ext_vector_type(8)));
typedef unsigned int u32x2 __attribute__((ext_vector_type(2)));
typedef unsigned int u32x4 __attribute__((ext_vector_type(4)));

#define DEVFN static __device__ __forceinline__

constexpr int S_ = 2048;   // sequence (also group-position count)
constexpr int E_ = 512;    // embed
constexpr int D_ = 8;      // head dim
constexpr int P_ = 64;     // qkv proj dim
// 1/(sqrt(8)*ln2)  : exp(s/sqrt(8)) == exp2(s * C2)
constexpr float C2 = 0.35355339059327373f * 1.4426950408889634f;

// Grouping (reshape trap): reference reshapes (B,S,64)->(64,2048,8) row-major:
// group g = b*8 + (s>>8), position p = (s&255)*8 + head, d = channel&7.

// workspace layout (bytes), ~6.6 MB total (poison evidence: ws is ~256 MB)
constexpr size_t FLAGA_OFF = 0;                                  // int[256]
constexpr size_t WT_OFF    = 1024;                               // Wt[192][512] bf16
constexpr size_t WUT_OFF   = WT_OFF + (size_t)192 * 512 * 2;     // Wut[512][64] bf16
constexpr size_t QG_OFF    = WUT_OFF + (size_t)512 * 64 * 2;     // Q [64g][2048][8] bf16
constexpr size_t KG_OFF    = QG_OFF + (size_t)64 * 2048 * 8 * 2; // K [64g][2048][8] bf16
constexpr size_t VTG_OFF   = KG_OFF + (size_t)64 * 2048 * 8 * 2; // V^T pi-layout bf16

DEVFN short f2bf(float f) {  // fp32 -> bf16 (RNE)
  unsigned u = __builtin_bit_cast(unsigned, f);
  return (short)((u + 0x7FFFu + ((u >> 16) & 1u)) >> 16);
}

DEVFN unsigned pkbf(float lo, float hi) {  // packed bf16 pair
  unsigned r;
  asm("v_cvt_pk_bf16_f32 %0, %1, %2" : "=v"(r) : "v"(lo), "v"(hi));
  return r;
}

DEVFN float fexp2(float x) {  // raw v_exp_f32 (args bounded; no OCML fixups)
#if __has_builtin(__builtin_amdgcn_exp2f)
  return __builtin_amdgcn_exp2f(x);
#else
  return exp2f(x);
#endif
}

DEVFN f32x16 mfma32(s16x8 a, s16x8 b, f32x16 c) {
  return __builtin_amdgcn_mfma_f32_32x32x16_bf16(a, b, c, 0, 0, 0);
}

DEVFN f32x16 zero16() {
  f32x16 z = {0,0,0,0,0,0,0,0,0,0,0,0,0,0,0,0};
  return z;
}

// ---------------- kernel 0: weight prep (bf16 transposed) + mask-zero flags ------
__global__ __launch_bounds__(256)
void prep_kernel(const float* __restrict__ Wq, const float* __restrict__ Wk,
                 const float* __restrict__ Wv, const float* __restrict__ Wu,
                 const float* __restrict__ maskm, short* __restrict__ WT,
                 short* __restrict__ WUT, int* __restrict__ flagA)
{
  int bid = blockIdx.x, tid = threadIdx.x;
  if (bid < 48) {                       // Wt[n][k] = W[k][n], n<192 k<512
    int base = (bid * 256 + tid) * 8;
#pragma unroll
    for (int j = 0; j < 8; ++j) {
      int idx = base + j;
      int n = idx >> 9, k = idx & 511;
      const float* W = (n < 64) ? Wq : ((n < 128) ? Wk : Wv);
      WT[idx] = f2bf(W[k * 64 + (n & 63)]);
    }
  } else if (bid < 56) {                // Wut[n][k] = Wu[k][n], n<512 k<64
    int base = ((bid - 48) * 256 + tid) * 16;
#pragma unroll
    for (int j = 0; j < 16; ++j) {
      int idx = base + j;
      int n = idx >> 6, k = idx & 63;
      WUT[idx] = f2bf(Wu[k * 512 + n]);
    }
  } else {                              // mask all-zero check -> flagA[bid-56]
    __shared__ int bf_;
    if (tid == 0) bf_ = 0;
    __syncthreads();
    const f32x4* m4 = (const f32x4*)maskm;
    int base = (bid - 56) * 4096;
    unsigned any = 0;
#pragma unroll
    for (int i = 0; i < 16; ++i) {
      f32x4 v = m4[base + i * 256 + tid];
      any |= __builtin_bit_cast(unsigned, v[0]) | __builtin_bit_cast(unsigned, v[1])
           | __builtin_bit_cast(unsigned, v[2]) | __builtin_bit_cast(unsigned, v[3]);
    }
    if (any != 0) atomicOr(&bf_, 1);    // LDS atomic; -0.0 nonzero: safe (slow path)
    __syncthreads();
    if (tid == 0) flagA[bid - 56] = bf_; // plain store, no global init needed
  }
}

// ---------------- kernel 1: QKV projection  x[16384,512] @ W -> bf16 group layouts
// Q pre-scaled by C2. V^T written pi-permuted [g][t][d][slot] so attn's PV
// A-operand key order matches the QK C-layout key order (no P transpose needed).
__global__ __launch_bounds__(384)
void proj_kernel(const float* __restrict__ x, const short* __restrict__ WT,
                 const float* __restrict__ bq, const float* __restrict__ bk,
                 const float* __restrict__ bv, short* __restrict__ QG,
                 short* __restrict__ KG, short* __restrict__ VTG)
{
  __shared__ short xl[32 * 520];        // x tile bf16, row stride 520 (bank pad)
  int tid = threadIdx.x;
  int mb = blockIdx.x * 32;
  for (int i = tid; i < 32 * 128; i += 384) {
    int row = i >> 7, c4 = i & 127;
    f32x4 v = *(const f32x4*)(x + (size_t)(mb + row) * E_ + c4 * 4);
    u32x2 w;
    w[0] = pkbf(v[0], v[1]);
    w[1] = pkbf(v[2], v[3]);
    *(u32x2*)(&xl[row * 520 + c4 * 4]) = w;
  }
  __syncthreads();
  int lane = tid & 63, wvi = tid >> 6;  // 6 waves, each an n-strip of 32
  int l31 = lane & 31, h = lane >> 5;
  int nstrip = wvi * 32;
  f32x16 acc = zero16();
#pragma unroll 4
  for (int kk = 0; kk < E_; kk += 16) { // C^T = Wt * x^T
    s16x8 af = *(const s16x8*)(WT + (size_t)(nstrip + l31) * E_ + kk + 8 * h);
    s16x8 bf = *(const s16x8*)(&xl[l31 * 520 + kk + 8 * h]);
    acc = mfma32(af, bf, acc);
  }
  int token = mb + l31;
  int bidx = token >> 11, s = token & 2047;
  int gg = bidx * 8 + (s >> 8);         // group = batch*8 + chunk
#pragma unroll
  for (int i = 0; i < 4; ++i) {
    int n0 = nstrip + 8 * i + 4 * h;    // 4 consecutive n per reg quad
    int proj = n0 >> 6;
    int wi = n0 & 63;
    int head = wi >> 3, db = wi & 7;    // db = 4h
    const float* bias = (proj == 0) ? bq : ((proj == 1) ? bk : bv);
    float sc = (proj == 0) ? C2 : 1.0f; // fold softmax scale into Q
    float f0 = (acc[4*i+0] + bias[wi+0]) * sc;
    float f1 = (acc[4*i+1] + bias[wi+1]) * sc;
    float f2 = (acc[4*i+2] + bias[wi+2]) * sc;
    float f3 = (acc[4*i+3] + bias[wi+3]) * sc;
    int p = ((s & 255) << 3) + head;    // group position = (s%256)*8 + head
    if (proj == 2) {                    // V^T: [g][t=p>>4][d][sigma(p&15)]
      int k16 = p & 15;
      int slot = (k16 & 3) + ((k16 >> 2) & 1) * 8 + (k16 >> 3) * 4;
      size_t vb = (size_t)gg * (S_ * D_) + (size_t)(p >> 4) * 128 + slot;
      VTG[vb + (db+0)*16] = f2bf(f0);
      VTG[vb + (db+1)*16] = f2bf(f1);
      VTG[vb + (db+2)*16] = f2bf(f2);
      VTG[vb + (db+3)*16] = f2bf(f3);
    } else {
      short* dst = (proj == 0) ? QG : KG;
      u32x2 o;
      o[0] = pkbf(f0, f1);
      o[1] = pkbf(f2, f3);
      *(u32x2*)(dst + ((size_t)gg * S_ + p) * D_ + db) = o;
    }
  }
}

// per-32-key-tile body of the attention main loop
#define ATTN_TILE(kb, USEMASK)                                          \
  {                                                                     \
    s16x8 kf = *(const s16x8*)kptr; kptr += kstride;                    \
    f32x16 st = mfma32(kf, qf, zero16());                               \
    s16x8 va1 = *(const s16x8*)vptr;                                    \
    s16x8 va2 = *(const s16x8*)(vptr + 144);                            \
    vptr += 288;                                                        \
    float p[16];                                                        \
    _Pragma("unroll")                                                   \
    for (int r = 0; r < 16; ++r) {                                      \
      float sv = st[r];                                                 \
      if (USEMASK) {                                                    \
        int key = (kb) + (r & 3) + 8 * (r >> 2) + 4 * h;                \
        sv += maskm[(size_t)q * S_ + key] * C2;                         \
      }                                                                 \
      p[r] = fexp2(sv);                                                 \
    }                                                                   \
    u32x4 b1, b2;                                                       \
    b1[0] = pkbf(p[0],  p[1]);  b1[1] = pkbf(p[2],  p[3]);              \
    b1[2] = pkbf(p[4],  p[5]);  b1[3] = pkbf(p[6],  p[7]);              \
    b2[0] = pkbf(p[8],  p[9]);  b2[1] = pkbf(p[10], p[11]);             \
    b2[2] = pkbf(p[12], p[13]); b2[3] = pkbf(p[14], p[15]);             \
    acc = mfma32(va1, __builtin_bit_cast(s16x8, b1), acc);              \
    acc = mfma32(va2, __builtin_bit_cast(s16x8, b2), acc);              \
  }

// ---------------- kernel 2: fused attention + output GEMM ------------------------
// Per block: one (group g, 256-q chunk) = complete attn rows for 32 consecutive
// tokens; epilogue computes out[32][512] = ATTtile @ Wu + bu directly.
__global__ __launch_bounds__(512, 4)
void attn_kernel(const short* __restrict__ QG, const short* __restrict__ KG,
                 const short* __restrict__ VTG, const float* __restrict__ maskm,
                 const int* __restrict__ flagA, const short* __restrict__ WUT,
                 const float* __restrict__ bu, float* __restrict__ out)
{
  __shared__ short K_lds[S_ * D_];          // [key][8]            32KB
  __shared__ short V_lds[128 * 9 * 16];     // [t][d(8)+ones][16]  36KB
  __shared__ short A_lds[32 * 68];          // attn tile [32 tok][64+pad] 4.25KB
  __shared__ short Z_lds[8];                // zero block (h=1 K reads)
  __shared__ int   sm_flag;
  int bid = blockIdx.x;
  int swz = (bid & 7) * 64 + (bid >> 3);    // XCD-chunked swizzle (512 = 8*64)
  int g  = swz >> 3;
  int qb = (swz & 7) * 256;
  int tid = threadIdx.x;
  {
    const u32x4* ks = (const u32x4*)(KG  + (size_t)g * (S_ * D_));
    const u32x4* vs = (const u32x4*)(VTG + (size_t)g * (S_ * D_));
    u32x4* kd = (u32x4*)K_lds;
#pragma unroll
    for (int it = 0; it < 4; ++it) {
      int i = tid + it * 512;
      kd[i] = ks[i];
      u32x4 v = vs[i];
      int t = i >> 4, rem = i & 15;         // rem = d*2 + half
      *(u32x4*)(&V_lds[t * 144 + rem * 8]) = v;
    }
    if (tid < 8) Z_lds[tid] = 0;
    unsigned one2 = 0x3F803F80u;            // ones row d=8 (denominator)
    u32x2 o2; o2[0] = one2; o2[1] = one2;
    int t = tid >> 2, qr = tid & 3;
    *(u32x2*)(&V_lds[t * 144 + 128 + qr * 4]) = o2;
    if (tid < 64) {                         // gather mask flags (256 ints)
      const u32x4* fa4 = (const u32x4*)flagA;
      u32x4 f = fa4[tid];
      unsigned anyf = f[0] | f[1] | f[2] | f[3];
      unsigned long long bb = __ballot(anyf != 0);
      if (tid == 0) sm_flag = (bb != 0ull) ? 1 : 0;
    }
  }
  __syncthreads();

  int lane = tid & 63, wvi = tid >> 6;      // 8 waves, each a 32-q strip
  int l31 = lane & 31, h = lane >> 5;
  int q = qb + wvi * 32 + l31;              // this lane's q position (C column)
  bool hi = (h != 0);
  int dcl = (l31 < 8) ? l31 : 8;            // V row (clamped to ones row)
  s16x8 zero8 = {0,0,0,0,0,0,0,0};

  s16x8 qf = hi ? zero8
                : *(const s16x8*)(QG + ((size_t)g * S_ + q) * D_);
  const short* kptr = hi ? Z_lds : &K_lds[l31 * 8];
  int kstride = hi ? 0 : 32 * 8;            // shorts per 32-key tile
  const short* vptr = &V_lds[dcl * 16 + 8 * h];
  f32x16 acc = zero16();
  bool usemask = (sm_flag != 0);

  if (!usemask) {
#pragma unroll 2
    for (int kb = 0; kb < S_; kb += 32) ATTN_TILE(kb, false)
  } else {
    for (int kb = 0; kb < S_; kb += 32) ATTN_TILE(kb, true)
  }
  // denominator: C row 8 (ones row) = acc[4] of h=0 lanes; share via shfl
  float d0 = acc[4];
  float dp = __shfl_xor(d0, 32, 64);
  float den = hi ? dp : d0;
  float inv = __builtin_amdgcn_rcpf(den);
  u32x2 o;
  o[0] = pkbf(acc[0] * inv, acc[1] * inv);
  o[1] = pkbf(acc[2] * inv, acc[3] * inv);
  // attn tile -> LDS: token-local row = (q-qb)>>3, channel = (q&7)*8 + d
  int local = wvi * 4 + (l31 >> 3);
  int col = (l31 & 7) * 8 + 4 * h;
  *(u32x2*)(&A_lds[local * 68 + col]) = o;
  __syncthreads();
  // out GEMM: out[32 tok][512] = A @ Wu + bu; wave wvi owns n-strip [wvi*64,+64)
  int nb = wvi * 64;
  f32x16 accA = zero16(), accB = zero16();
#pragma unroll
  for (int kk = 0; kk < 64; kk += 16) {
    s16x8 af  = *(const s16x8*)(&A_lds[l31 * 68 + kk + 8 * h]);
    s16x8 bfA = *(const s16x8*)(WUT + (size_t)(nb + l31) * P_ + kk + 8 * h);
    s16x8 bfB = *(const s16x8*)(WUT + (size_t)(nb + 32 + l31) * P_ + kk + 8 * h);
    accA = mfma32(af, bfA, accA);
    accB = mfma32(af, bfB, accB);
  }
  size_t token_base = (size_t)(g >> 3) * S_ + (g & 7) * 256 + (qb >> 3);
  size_t obase = token_base * E_;
  int nA = nb + l31, nB = nb + 32 + l31;
  float biasA = bu[nA], biasB = bu[nB];
#pragma unroll
  for (int r = 0; r < 16; ++r) {
    int m = (r & 3) + 8 * (r >> 2) + 4 * h;
    out[obase + (size_t)m * E_ + nA] = accA[r] + biasA;
    out[obase + (size_t)m * E_ + nB] = accB[r] + biasB;
  }
}

extern "C" void kernel_launch(void* const* d_in, const int* in_sizes, int n_in,
                              void* d_out, int out_size, void* d_ws, size_t ws_size,
                              hipStream_t stream) {
  const float* x     = (const float*)d_in[0];
  const float* maskm = (const float*)d_in[1];
  const float* Wq    = (const float*)d_in[2];
  const float* bq    = (const float*)d_in[3];
  const float* Wk    = (const float*)d_in[4];
  const float* bk    = (const float*)d_in[5];
  const float* Wv    = (const float*)d_in[6];
  const float* bv    = (const float*)d_in[7];
  const float* Wu    = (const float*)d_in[8];
  const float* bu    = (const float*)d_in[9];
  float* out = (float*)d_out;
  char* ws = (char*)d_ws;
  int*   flagA = (int*)(ws + FLAGA_OFF);
  short* WT    = (short*)(ws + WT_OFF);
  short* WUT   = (short*)(ws + WUT_OFF);
  short* QG    = (short*)(ws + QG_OFF);
  short* KG    = (short*)(ws + KG_OFF);
  short* VTG   = (short*)(ws + VTG_OFF);

  prep_kernel<<<312, 256, 0, stream>>>(Wq, Wk, Wv, Wu, maskm, WT, WUT, flagA);
  proj_kernel<<<512, 384, 0, stream>>>(x, WT, bq, bk, bv, QG, KG, VTG);
  attn_kernel<<<512, 512, 0, stream>>>(QG, KG, VTG, maskm, flagA, WUT, bu, out);
}